// Round 7
// baseline (1492.426 us; speedup 1.0000x reference)
//
#include <hip/hip_runtime.h>
#include <math.h>

#define NEGV -1000000000.0f
#define EPSV 1e-38f

__device__ __forceinline__ int tri(int i, int j) { return ((j * (j + 1)) >> 1) + i; }
__device__ __forceinline__ float la2(float a, float c) {
  float mx = fmaxf(a, c), mn = fminf(a, c);
  return mx + log1pf(__expf(mn - mx));
}

// ---------------------------------------------------------------- frontend + theta
// 512 blocks x 256. Block bt: LN(512)->GELU MLP(128)->24 logits->log_softmax -> Phi.
// Also normalizes theta rows into et_g (et = exp(theta_log), tm dropped — exact).
__global__ void __launch_bounds__(256) frontend_kernel(
    const float* __restrict__ g_seq, const float* __restrict__ Theta,
    const float* __restrict__ lng, const float* __restrict__ lnb,
    const float* __restrict__ W1, const float* __restrict__ bb1,
    const float* __restrict__ W2, const float* __restrict__ bb2,
    float* __restrict__ Phi_g, float* __restrict__ et_g) {
  __shared__ __align__(16) float g[512];
  __shared__ __align__(16) float2 red[256];
  __shared__ float hb[128];
  __shared__ float ob[32];
  __shared__ float sc[8];
  const int tid = threadIdx.x, blk = blockIdx.x;

  float2 raw = ((const float2*)(g_seq + (size_t)blk * 512))[tid];
  red[tid] = make_float2(raw.x + raw.y, raw.x * raw.x + raw.y * raw.y);
  __syncthreads();
  if (tid < 128) { float2 o = red[tid + 128], m = red[tid]; red[tid] = make_float2(m.x + o.x, m.y + o.y); }
  __syncthreads();
  if (tid < 64) {
    float2 v = red[tid], o = red[tid + 64];
    v.x += o.x; v.y += o.y;
    for (int off = 32; off; off >>= 1) { v.x += __shfl_xor(v.x, off); v.y += __shfl_xor(v.y, off); }
    if (tid == 0) {
      float mu = v.x / 512.0f;
      float var = v.y / 512.0f - mu * mu;
      sc[0] = mu; sc[1] = rsqrtf(var + 1e-5f);
    }
  }
  __syncthreads();
  float mu = sc[0], rstd = sc[1];
  g[2 * tid]     = (raw.x - mu) * rstd * lng[2 * tid]     + lnb[2 * tid];
  g[2 * tid + 1] = (raw.y - mu) * rstd * lng[2 * tid + 1] + lnb[2 * tid + 1];
  __syncthreads();
  {
    int j = tid & 127, hh = tid >> 7, c0 = hh * 256;
    float a0 = 0, a1 = 0, a2 = 0, a3 = 0;
    for (int c = 0; c < 256; c += 4) {
      a0 = fmaf(g[c0 + c],     W1[(c0 + c) * 128 + j],     a0);
      a1 = fmaf(g[c0 + c + 1], W1[(c0 + c + 1) * 128 + j], a1);
      a2 = fmaf(g[c0 + c + 2], W1[(c0 + c + 2) * 128 + j], a2);
      a3 = fmaf(g[c0 + c + 3], W1[(c0 + c + 3) * 128 + j], a3);
    }
    ((float*)red)[tid] = (a0 + a1) + (a2 + a3);
  }
  __syncthreads();
  if (tid < 128) {
    float a = ((float*)red)[tid] + ((float*)red)[tid + 128] + bb1[tid];
    hb[tid] = 0.5f * a * (1.0f + erff(a * 0.70710678118654752f));
  }
  __syncthreads();
  if (tid < 192) {
    int n = tid >> 3, q = tid & 7;
    float a = 0;
    for (int k = 0; k < 16; k++) a = fmaf(hb[q * 16 + k], W2[(q * 16 + k) * 24 + n], a);
    ((float*)red)[tid] = a;
  }
  __syncthreads();
  if (tid < 24) {
    float a = bb2[tid];
    for (int q = 0; q < 8; q++) a += ((float*)red)[tid * 8 + q];
    ob[tid] = a;
  }
  __syncthreads();
  if (tid == 0) {
    float m = ob[0];
    for (int n = 1; n < 24; n++) m = fmaxf(m, ob[n]);
    float s = 0;
    for (int n = 0; n < 24; n++) s += __expf(ob[n] - m);
    sc[2] = m + __logf(s);
  }
  __syncthreads();
  if (tid < 24)
    Phi_g[((size_t)(blk >> 5) * 24 + tid) * 32 + (blk & 31)] = ob[tid] - sc[2];

  // theta rows: row blk, and row 512+blk for blk<64
  if (tid < 64) {
    int z = tid & 31;
    bool up = tid >= 32;
    int row = up ? (512 + blk) : blk;
    bool valid = (!up) || (blk < 64);
    float v = (z < 24 && valid) ? Theta[row * 24 + z] : NEGV;
    float m = v;
    for (int off = 16; off; off >>= 1) m = fmaxf(m, __shfl_xor(m, off));
    float e = (z < 24 && valid) ? __expf(v - m) : 0.f;
    float s = e;
    for (int off = 16; off; off >>= 1) s += __shfl_xor(s, off);
    float lse = m + __logf(s);
    if (z < 24 && valid) et_g[row * 24 + z] = __expf(v - lse);
  }
}

// ---------------------------------------------------------------- chart
// 16 blocks x 1024 (one batch per block, one CU). beta + et in LDS; alpha (aL/aR
// split) in block-private global. Levels separated by __syncthreads only.
// 4 span-groups of 256 threads per block. GSTRIDE=2200 (r5 fix: no msc aliasing).
// r6 fix: root alpha folded into the fill loop — the separate tid==0 store of
// aLb[11904]=0 raced tid 640's NEGV fill of the same index (no sync between).
constexpr int GSTRIDE = 2200;
__global__ void __launch_bounds__(1024) chart_kernel(
    const float* __restrict__ et_g, const float* __restrict__ Phi_g,
    float* __restrict__ aL_g, float* __restrict__ aR_g,
    float* __restrict__ pnt_g, float* __restrict__ logZ_g) {
  __shared__ __align__(16) float etL[13824];        // et[x*576 + y*24 + z]
  __shared__ __align__(16) float bt[12672];         // beta[tri(i,j)*24 + n]
  __shared__ __align__(16) float grp[4][GSTRIDE];
  const int tid = threadIdx.x, b = blockIdx.x;
  const int gid = tid >> 8, lt = tid & 255;
  float* eA  = grp[gid];
  float* eB  = eA + 744;
  float* rr  = eB + 744;
  float* mLs = rr + 576;
  float* mRs = mLs + 32;
  float* msc = mRs + 32;       // 48 slots: [0..23] ea, [24] ma
  float* aLb = aL_g + (size_t)b * 12672;
  float* aRb = aR_g + (size_t)b * 12672;

  // stage et, init alpha (root folded in — no race), stage Phi diagonal
  for (int i4 = tid; i4 < 3456; i4 += 1024)
    ((float4*)etL)[i4] = ((const float4*)et_g)[i4];
  for (int idx = tid; idx < 12672; idx += 1024) {
    aLb[idx] = (idx == 496 * 24) ? 0.f : NEGV;  // root alpha(0,31)[0] = 0
    aRb[idx] = NEGV;
  }
  if (tid < 768) {
    int n = tid >> 5, t = tid & 31;
    bt[tri(t, t) * 24 + n] = Phi_g[((size_t)b * 24 + n) * 32 + t];
  }
  __syncthreads();

  //================ inside ================
  for (int l = 2; l <= 32; l++) {
    int S = l - 1, P = 33 - l, SN = S * 24;
    for (int r0 = 0; r0 < P; r0 += 4) {
      int i = r0 + gid, j = i + S;
      bool act = (i < P);
      // phase a: per-split maxes (8 threads/split)
      if (act && lt < 8 * S) {
        int s = lt >> 3, q = lt & 7, y0 = q * 3;
        const float* L = bt + tri(i, i + s) * 24;
        const float* R = bt + tri(i + s + 1, j) * 24;
        float pa = fmaxf(fmaxf(L[y0], L[y0 + 1]), L[y0 + 2]);
        float pb = fmaxf(fmaxf(R[y0], R[y0 + 1]), R[y0 + 2]);
        for (int off = 4; off; off >>= 1) {
          pa = fmaxf(pa, __shfl_xor(pa, off));
          pb = fmaxf(pb, __shfl_xor(pb, off));
        }
        if (q == 0) { mRs[s] = pb; mLs[s] = pa + pb; }  // mLs holds msum
      }
      __syncthreads();
      // phase b: M + exp staging
      float M = NEGV;
      if (act) {
        for (int s = 0; s < S; s++) M = fmaxf(M, mLs[s]);
        for (int idx = lt; idx < SN; idx += 256) {
          int s = idx / 24, y = idx - s * 24;
          float m_ = mRs[s];
          eA[idx] = __expf(bt[tri(i, i + s) * 24 + y] + m_ - M);
          eB[idx] = __expf(bt[tri(i + s + 1, j) * 24 + y] - m_);
        }
      }
      __syncthreads();
      // phase c: r[y,z] = sum_s eA[s,y] * eB[s,z]
      if (act && lt < 144) {
        int y = lt / 6, zq = lt % 6;
        float4 acc = make_float4(0, 0, 0, 0);
        for (int s = 0; s < S; s++) {
          float a = eA[s * 24 + y];
          float4 b4 = ((float4*)(eB + s * 24))[zq];
          acc.x = fmaf(a, b4.x, acc.x); acc.y = fmaf(a, b4.y, acc.y);
          acc.z = fmaf(a, b4.z, acc.z); acc.w = fmaf(a, b4.w, acc.w);
        }
        ((float4*)rr)[y * 6 + zq] = acc;
      }
      __syncthreads();
      // phase d: score[x] = sum_p et[x,p] * r[p]; octet shuffle reduce
      if (act && lt < 192) {
        int x = lt >> 3, c8 = lt & 7;
        const float4* e4 = (const float4*)(etL + x * 576 + c8 * 72);
        const float4* r4 = (const float4*)(rr + c8 * 72);
        float a0 = 0, a1 = 0;
#pragma unroll
        for (int q = 0; q < 18; q += 2) {
          float4 e = e4[q], r = r4[q];
          a0 = fmaf(e.x, r.x, fmaf(e.y, r.y, fmaf(e.z, r.z, fmaf(e.w, r.w, a0))));
          float4 e2 = e4[q + 1], r2 = r4[q + 1];
          a1 = fmaf(e2.x, r2.x, fmaf(e2.y, r2.y, fmaf(e2.z, r2.z, fmaf(e2.w, r2.w, a1))));
        }
        float acc = a0 + a1;
        acc += __shfl_xor(acc, 4);
        acc += __shfl_xor(acc, 2);
        acc += __shfl_xor(acc, 1);
        if (c8 == 0) bt[tri(i, j) * 24 + x] = M + __logf(fmaxf(acc, EPSV));
      }
    }
    __syncthreads();  // level boundary
  }
  if (tid == 0) logZ_g[b] = bt[496 * 24];

  //================ outside ================
  for (int l = 32; l >= 2; l--) {
    int S = l - 1, P = 33 - l, SN = S * 24;
    for (int r0 = 0; r0 < P; r0 += 4) {
      int i = r0 + gid, j = i + S;
      bool act = (i < P);
      // phase a: child split maxes + parent alpha
      if (act) {
        if (lt < 8 * S) {
          int s = lt >> 3, q = lt & 7, y0 = q * 3;
          const float* L = bt + tri(i, i + s) * 24;
          const float* R = bt + tri(i + s + 1, j) * 24;
          float pl = fmaxf(fmaxf(L[y0], L[y0 + 1]), L[y0 + 2]);
          float pr = fmaxf(fmaxf(R[y0], R[y0 + 1]), R[y0 + 2]);
          for (int off = 4; off; off >>= 1) {
            pl = fmaxf(pl, __shfl_xor(pl, off));
            pr = fmaxf(pr, __shfl_xor(pr, off));
          }
          if (q == 0) { mLs[s] = pl; mRs[s] = pr; }
        }
        if (lt < 32) {
          float av = NEGV;
          if (lt < 24) av = la2(aLb[tri(i, j) * 24 + lt], aRb[tri(i, j) * 24 + lt]);
          float m = av;
          for (int off = 16; off; off >>= 1) m = fmaxf(m, __shfl_xor(m, off));
          if (lt < 24) msc[lt] = __expf(av - m);
          if (lt == 0) msc[24] = m;
        }
      }
      __syncthreads();
      // phase b: w[y,z] = sum_x et[x,y,z]*ea[x]; exp staging of children
      if (act) {
        for (int p = lt; p < 576; p += 256) {
          float acc = 0;
#pragma unroll
          for (int x = 0; x < 24; x++) acc = fmaf(etL[x * 576 + p], msc[x], acc);
          rr[p] = acc;
        }
        for (int idx = lt; idx < SN; idx += 256) {
          int s = idx / 24, y = idx - s * 24;
          eA[idx] = __expf(bt[tri(i, i + s) * 24 + y] - mLs[s]);      // left
          eB[idx] = __expf(bt[tri(i + s + 1, j) * 24 + y] - mRs[s]);  // right
        }
      }
      __syncthreads();
      // phase c: cL and cR updates (unique targets per level in aL / aR)
      if (act) {
        float ma = msc[24];
        for (int u = lt; u < 2 * SN; u += 256) {
          if (u < SN) {
            int s = u / 24, y = u - s * 24;
            const float4* w4 = (const float4*)(rr + y * 24);
            const float4* r4 = (const float4*)(eB + s * 24);
            float acc = 0;
#pragma unroll
            for (int q = 0; q < 6; q++) {
              float4 a = w4[q], c4 = r4[q];
              acc = fmaf(a.x, c4.x, fmaf(a.y, c4.y, fmaf(a.z, c4.z, fmaf(a.w, c4.w, acc))));
            }
            float val = __logf(fmaxf(acc, EPSV)) + ma + mRs[s];
            float* t = aLb + tri(i, i + s) * 24 + y;
            *t = la2(*t, val);
          } else {
            int u2 = u - SN;
            int s = u2 / 24, z = u2 - s * 24;
            float acc = 0;
            for (int y = 0; y < 24; y++) acc = fmaf(rr[y * 24 + z], eA[s * 24 + y], acc);
            float val = __logf(fmaxf(acc, EPSV)) + ma + mLs[s];
            float* t = aRb + tri(i + s + 1, j) * 24 + z;
            *t = la2(*t, val);
          }
        }
      }
      __syncthreads();
    }
  }

  //================ p_nt ================
  float logZ = bt[496 * 24];
  if (tid < 768) {
    int n = tid >> 5, t = tid & 31;
    int d = tri(t, t) * 24 + n;
    pnt_g[(size_t)b * 768 + tid] = __expf(la2(aLb[d], aRb[d]) + bt[d] - logZ);
  }
}

// ---------------------------------------------------------------- mask logits + loss
__global__ void __launch_bounds__(256) mask_kernel(
    const float* __restrict__ pnt, const float* __restrict__ vocab,
    const float* __restrict__ logZ_g, float* __restrict__ out) {
  int b = blockIdx.y;
  int v = blockIdx.x * 256 + threadIdx.x;  // V = 125*256
  __shared__ float p[768];                 // [n*32 + t]
  for (int idx = threadIdx.x; idx < 768; idx += 256) p[idx] = pnt[(size_t)b * 768 + idx];
  __syncthreads();
  float vr[24];
#pragma unroll
  for (int n = 0; n < 24; n++) vr[n] = vocab[n * 32000 + v];
  float* ob = out + (size_t)b * 32 * 32000 + v;
  for (int t4 = 0; t4 < 32; t4 += 4) {
    float a0 = 1e-6f, a1 = 1e-6f, a2 = 1e-6f, a3 = 1e-6f;
#pragma unroll 6
    for (int n = 0; n < 24; n++) {
      float4 pv = *(const float4*)(p + n * 32 + t4);
      a0 = fmaf(pv.x, vr[n], a0); a1 = fmaf(pv.y, vr[n], a1);
      a2 = fmaf(pv.z, vr[n], a2); a3 = fmaf(pv.w, vr[n], a3);
    }
    ob[(size_t)(t4 + 0) * 32000] = __logf(a0);
    ob[(size_t)(t4 + 1) * 32000] = __logf(a1);
    ob[(size_t)(t4 + 2) * 32000] = __logf(a2);
    ob[(size_t)(t4 + 3) * 32000] = __logf(a3);
  }
  if (blockIdx.x == 0 && b == 0 && threadIdx.x == 0) {
    float s = 0;
    for (int q = 0; q < 16; q++) s += logZ_g[q];
    out[16384000] = -s / 16.0f;
  }
}

// ---------------------------------------------------------------- launch
extern "C" void kernel_launch(void* const* d_in, const int* in_sizes, int n_in,
                              void* d_out, int out_size, void* d_ws, size_t ws_size,
                              hipStream_t stream) {
  (void)in_sizes; (void)n_in; (void)out_size; (void)ws_size;
  const float* g_seq = (const float*)d_in[0];
  const float* Theta = (const float*)d_in[1];
  const float* vocab = (const float*)d_in[2];
  const float* lng   = (const float*)d_in[3];
  const float* lnb   = (const float*)d_in[4];
  const float* W1    = (const float*)d_in[5];
  const float* bb1   = (const float*)d_in[6];
  const float* W2    = (const float*)d_in[7];
  const float* bb2   = (const float*)d_in[8];
  float* out = (float*)d_out;

  float* ws = (float*)d_ws;
  float* Phi_g  = ws;                  // 12288
  float* et_g   = ws + 12288;          // 13824
  float* aL_g   = ws + 26112;          // 16*12672 = 202752
  float* aR_g   = aL_g + 202752;       // 202752
  float* pnt_g  = aR_g + 202752;       // 12288
  float* logZ_g = pnt_g + 12288;       // 16

  frontend_kernel<<<dim3(512), dim3(256), 0, stream>>>(
      g_seq, Theta, lng, lnb, W1, bb1, W2, bb2, Phi_g, et_g);
  chart_kernel<<<dim3(16), dim3(1024), 0, stream>>>(
      et_g, Phi_g, aL_g, aR_g, pnt_g, logZ_g);
  mask_kernel<<<dim3(125, 16), dim3(256), 0, stream>>>(pnt_g, vocab, logZ_g, out);
}

// Round 8
// 506.066 us; speedup vs baseline: 2.9491x; 2.9491x over previous
//
#include <hip/hip_runtime.h>
#include <math.h>

#define NEGV -1000000000.0f
#define EPSV 1e-38f

constexpr int BSTRIDE = 528 * 32;   // beta floats per batch (128B-padded cells, write-once)
constexpr int ASTRIDE = 528 * 24;   // aL/aR floats per batch

__device__ __forceinline__ int tri(int i, int j) { return ((j * (j + 1)) >> 1) + i; }
__device__ __forceinline__ float la2(float a, float c) {
  float mx = fmaxf(a, c), mn = fminf(a, c);
  return mx + log1pf(__expf(mn - mx));
}
// relaxed agent-scope (sc1) ops — bypass L1/L2, hit the coherent point (r4-proven)
__device__ __forceinline__ void gstore(float* p, float v) {
  __hip_atomic_store(p, v, __ATOMIC_RELAXED, __HIP_MEMORY_SCOPE_AGENT);
}
__device__ __forceinline__ float gload(const float* p) {
  return __hip_atomic_load(p, __ATOMIC_RELAXED, __HIP_MEMORY_SCOPE_AGENT);
}
__device__ __forceinline__ void storeu(unsigned* p, unsigned v) {
  __hip_atomic_store(p, v, __ATOMIC_RELAXED, __HIP_MEMORY_SCOPE_AGENT);
}
__device__ __forceinline__ unsigned loadu(const unsigned* p) {
  return __hip_atomic_load(p, __ATOMIC_RELAXED, __HIP_MEMORY_SCOPE_AGENT);
}

// 512 blocks x 256 threads, cooperative. b = blk&15, local = blk>>4.
__global__ void __launch_bounds__(256, 2) mega_kernel(
    const float* __restrict__ g_seq, const float* __restrict__ Theta,
    const float* __restrict__ vocab, const float* __restrict__ lng,
    const float* __restrict__ lnb, const float* __restrict__ W1,
    const float* __restrict__ bb1, const float* __restrict__ W2,
    const float* __restrict__ bb2, float* __restrict__ out,
    float* __restrict__ et_g, float* __restrict__ beta_g,
    float* __restrict__ aL_g, float* __restrict__ aR_g,
    unsigned* __restrict__ cnt, float* __restrict__ logZg) {
  __shared__ __align__(16) float sm[16160];
  float* etL = sm;          // 13824
  float* wk = sm + 13824;   // 2336
  const int tid = threadIdx.x;
  const int blk = blockIdx.x;
  const int b = blk & 15, local = blk >> 4;
  unsigned* gcnt  = cnt;                    // init stage-2 (16 arrivals)
  unsigned* done  = cnt + 8;                // logZ done count
  unsigned* ibc   = cnt + 16 + b * 16;      // init stage-1 per batch
  unsigned* slots = cnt + 512 + b * 64;     // 32 single-writer arrival slots
  unsigned* go    = slots + 32;             // epoch flag
  float* bbase = beta_g + b * BSTRIDE;
  float* aLb = aL_g + b * ASTRIDE;
  float* aRb = aR_g + b * ASTRIDE;

  //================ phase 0: frontend (task bt = blk) ================
  {
    float* g = wk;                       // 512
    float2* red = (float2*)(wk + 512);   // 512
    float* hb = wk + 1024;               // 128
    float* ob = wk + 1152;               // 32
    float* sc = wk + 1184;               // 8
    float2 raw = ((const float2*)(g_seq + (size_t)blk * 512))[tid];
    red[tid] = make_float2(raw.x + raw.y, raw.x * raw.x + raw.y * raw.y);
    __syncthreads();
    if (tid < 128) { float2 o = red[tid + 128], m = red[tid]; red[tid] = make_float2(m.x + o.x, m.y + o.y); }
    __syncthreads();
    if (tid < 64) {
      float2 v = red[tid], o = red[tid + 64];
      v.x += o.x; v.y += o.y;
      for (int off = 32; off; off >>= 1) { v.x += __shfl_xor(v.x, off); v.y += __shfl_xor(v.y, off); }
      if (tid == 0) {
        float mu = v.x / 512.0f;
        float var = v.y / 512.0f - mu * mu;
        sc[0] = mu; sc[1] = rsqrtf(var + 1e-5f);
      }
    }
    __syncthreads();
    float mu = sc[0], rstd = sc[1];
    g[2 * tid]     = (raw.x - mu) * rstd * lng[2 * tid]     + lnb[2 * tid];
    g[2 * tid + 1] = (raw.y - mu) * rstd * lng[2 * tid + 1] + lnb[2 * tid + 1];
    __syncthreads();
    {
      int j = tid & 127, hh = tid >> 7, c0 = hh * 256;
      float a0 = 0, a1 = 0, a2 = 0, a3 = 0;
      for (int c = 0; c < 256; c += 4) {
        a0 = fmaf(g[c0 + c],     W1[(c0 + c) * 128 + j],     a0);
        a1 = fmaf(g[c0 + c + 1], W1[(c0 + c + 1) * 128 + j], a1);
        a2 = fmaf(g[c0 + c + 2], W1[(c0 + c + 2) * 128 + j], a2);
        a3 = fmaf(g[c0 + c + 3], W1[(c0 + c + 3) * 128 + j], a3);
      }
      ((float*)red)[tid] = (a0 + a1) + (a2 + a3);
    }
    __syncthreads();
    if (tid < 128) {
      float a = ((float*)red)[tid] + ((float*)red)[tid + 128] + bb1[tid];
      hb[tid] = 0.5f * a * (1.0f + erff(a * 0.70710678118654752f));
    }
    __syncthreads();
    if (tid < 192) {
      int n = tid >> 3, q = tid & 7;
      float a = 0;
      for (int k = 0; k < 16; k++) a = fmaf(hb[q * 16 + k], W2[(q * 16 + k) * 24 + n], a);
      ((float*)red)[tid] = a;
    }
    __syncthreads();
    if (tid < 24) {
      float a = bb2[tid];
      for (int q = 0; q < 8; q++) a += ((float*)red)[tid * 8 + q];
      ob[tid] = a;
    }
    __syncthreads();
    if (tid == 0) {
      float m = ob[0];
      for (int n = 1; n < 24; n++) m = fmaxf(m, ob[n]);
      float s = 0;
      for (int n = 0; n < 24; n++) s += __expf(ob[n] - m);
      sc[2] = m + __logf(s);
    }
    __syncthreads();
    if (tid < 24) {
      int fb = blk >> 5, ft = blk & 31;
      gstore(beta_g + (size_t)fb * BSTRIDE + tri(ft, ft) * 32 + tid, ob[tid] - sc[2]);
    }
  }
  // theta rows (tm dropped — exact; et = exp(theta_log) <= 1)
  if (tid < 64) {
    int z = tid & 31;
    bool up = tid >= 32;
    int row = up ? (512 + blk) : blk;
    bool valid = (!up) || (blk < 64);
    float v = (z < 24 && valid) ? Theta[row * 24 + z] : NEGV;
    float m = v;
    for (int off = 16; off; off >>= 1) m = fmaxf(m, __shfl_xor(m, off));
    float e = (z < 24 && valid) ? __expf(v - m) : 0.f;
    float s = e;
    for (int off = 16; off; off >>= 1) s += __shfl_xor(s, off);
    float lse = m + __logf(s);
    if (z < 24 && valid) gstore(et_g + row * 24 + z, __expf(v - lse));
  }
  // alpha init (aL||aR contiguous); root aL[b][tri(0,31)][0] = 0 folded in
  for (int idx = blk * 256 + tid; idx < 2 * 16 * ASTRIDE; idx += 131072) {
    float v = NEGV;
    if (idx < 16 * ASTRIDE && (idx % ASTRIDE) == 11904) v = 0.f;
    gstore(aL_g + idx, v);
  }
  // ---- init global barrier (two-stage, r4-proven) ----
  __builtin_amdgcn_s_waitcnt(0);
  __syncthreads();
  if (tid == 0) {
    __hip_atomic_fetch_add(ibc, 1u, __ATOMIC_RELAXED, __HIP_MEMORY_SCOPE_AGENT);
    if (local == 0) {
      while (loadu(ibc) < 32u) __builtin_amdgcn_s_sleep(2);
      __hip_atomic_fetch_add(gcnt, 1u, __ATOMIC_RELAXED, __HIP_MEMORY_SCOPE_AGENT);
    }
    while (loadu(gcnt) < 16u) __builtin_amdgcn_s_sleep(2);
  }
  __syncthreads();

  // stage et into LDS once (write-once region; plain vectorized loads safe)
  for (int i4 = tid; i4 < 3456; i4 += 256)
    ((float4*)etL)[i4] = ((const float4*)et_g)[i4];
  __syncthreads();

  //================ inside: 31 levels, slot/go barrier per level ================
  {
    float* eA = wk;           // 744
    float* eB = wk + 744;     // 744
    float* rr = wk + 1488;    // 576
    float* red2 = wk + 2064;  // 192
    float* mrl = wk + 2256;   // 32
    float* msm = wk + 2288;   // 32
    float* scal = wk + 2320;  // 16
    for (int l = 2; l <= 32; l++) {
      unsigned e = (unsigned)(l - 1);
      int S = l - 1, P = 33 - l;
      // wait for previous level's epoch
      if (tid == 0) { while (loadu(go) < e - 1) __builtin_amdgcn_s_sleep(1); }
      __syncthreads();
      if (local < P) {
        int i = local, j = i + S, SN = S * 24;
        for (int idx4 = tid; idx4 < 6 * S; idx4 += 256) {
          int s = idx4 / 6, q = idx4 - 6 * s;
          ((float4*)eA)[idx4] = ((const float4*)(bbase + (size_t)tri(i, i + s) * 32))[q];
          ((float4*)eB)[idx4] = ((const float4*)(bbase + (size_t)tri(i + s + 1, j) * 32))[q];
        }
        __syncthreads();
        if (tid < 8 * S) {
          int s = tid >> 3, q = tid & 7, y0 = q * 3;
          float pa = fmaxf(fmaxf(eA[s * 24 + y0], eA[s * 24 + y0 + 1]), eA[s * 24 + y0 + 2]);
          float pb = fmaxf(fmaxf(eB[s * 24 + y0], eB[s * 24 + y0 + 1]), eB[s * 24 + y0 + 2]);
          for (int off = 4; off; off >>= 1) {
            pa = fmaxf(pa, __shfl_xor(pa, off));
            pb = fmaxf(pb, __shfl_xor(pb, off));
          }
          if (q == 0) { mrl[s] = pb; msm[s] = pa + pb; }
        }
        __syncthreads();
        if (tid < 32) {
          float v = (tid < S) ? msm[tid] : NEGV;
          for (int off = 16; off; off >>= 1) v = fmaxf(v, __shfl_xor(v, off));
          if (tid == 0) scal[0] = v;
        }
        __syncthreads();
        float M = scal[0];
        for (int idx = tid; idx < SN; idx += 256) {
          int s = idx / 24;
          float m_ = mrl[s];
          eA[idx] = __expf(eA[idx] + m_ - M);
          eB[idx] = __expf(eB[idx] - m_);
        }
        __syncthreads();
        if (tid < 144) {
          int y = tid / 6, zq = tid % 6;
          float4 acc = make_float4(0, 0, 0, 0);
          for (int s = 0; s < S; s++) {
            float a = eA[s * 24 + y];
            float4 b4 = ((float4*)eB)[s * 6 + zq];
            acc.x = fmaf(a, b4.x, acc.x); acc.y = fmaf(a, b4.y, acc.y);
            acc.z = fmaf(a, b4.z, acc.z); acc.w = fmaf(a, b4.w, acc.w);
          }
          ((float4*)rr)[y * 6 + zq] = acc;
        }
        __syncthreads();
        if (tid < 192) {
          int x = tid >> 3, c = tid & 7;
          const float4* e4 = (const float4*)(etL + x * 576 + c * 72);
          const float4* r4 = (const float4*)(rr + c * 72);
          float a0 = 0, a1 = 0;
#pragma unroll
          for (int q = 0; q < 18; q += 2) {
            float4 ev = e4[q], rv = r4[q];
            a0 = fmaf(ev.x, rv.x, fmaf(ev.y, rv.y, fmaf(ev.z, rv.z, fmaf(ev.w, rv.w, a0))));
            float4 e2 = e4[q + 1], r2 = r4[q + 1];
            a1 = fmaf(e2.x, r2.x, fmaf(e2.y, r2.y, fmaf(e2.z, r2.z, fmaf(e2.w, r2.w, a1))));
          }
          red2[tid] = a0 + a1;
        }
        __syncthreads();
        if (tid < 24) {
          float a = 0;
          for (int q = 0; q < 8; q++) a += red2[tid * 8 + q];
          gstore(bbase + (size_t)tri(i, j) * 32 + tid, M + __logf(fmaxf(a, EPSV)));
        }
      }
      // ---- arrive (single-writer slot) + poller advances go ----
      __builtin_amdgcn_s_waitcnt(0);
      __syncthreads();
      if (tid == 0) storeu(slots + local, e);
      if (local == 0 && tid < 64) {
        for (;;) {
          unsigned v = e;
          if (tid < 32) v = loadu(slots + tid);
          if (__ballot(v >= e) == ~0ull) break;
          __builtin_amdgcn_s_sleep(1);
        }
        if (tid == 0) storeu(go, e);
      }
    }
  }
  if (local == 0 && tid == 0) {
    gstore(logZg + b, gload(bbase + 496 * 32));
    __hip_atomic_fetch_add(done, 1u, __ATOMIC_RELAXED, __HIP_MEMORY_SCOPE_AGENT);
  }

  //================ outside: 31 levels ================
  {
    float* w = wk;            // 576
    float* ebL = wk + 576;    // 744
    float* ebR = wk + 1320;   // 744
    float* mLs = wk + 2064;   // 32
    float* mRs = wk + 2096;   // 32
    float* ea24 = wk + 2128;  // 24
    float* scal = wk + 2320;  // 16
    for (int l = 32; l >= 2; l--) {
      unsigned e = (unsigned)(64 - l);
      int S = l - 1, P = 33 - l;
      if (tid == 0) { while (loadu(go) < e - 1) __builtin_amdgcn_s_sleep(1); }
      __syncthreads();
      if (local < P) {
        int i = local, j = i + S, SN = S * 24;
        if (tid < 32) {
          float av = NEGV;
          if (tid < 24) av = la2(gload(aLb + tri(i, j) * 24 + tid), gload(aRb + tri(i, j) * 24 + tid));
          float m = av;
          for (int off = 16; off; off >>= 1) m = fmaxf(m, __shfl_xor(m, off));
          if (tid < 24) ea24[tid] = __expf(av - m);
          if (tid == 0) scal[0] = m;
        }
        __syncthreads();
        float ma = scal[0];
        if (tid < 144) {
          int y = tid / 6, zq = tid % 6;
          float4 acc = make_float4(0, 0, 0, 0);
#pragma unroll 4
          for (int x = 0; x < 24; x++) {
            float a = ea24[x];
            float4 ev = ((const float4*)(etL + x * 576 + y * 24))[zq];
            acc.x = fmaf(a, ev.x, acc.x); acc.y = fmaf(a, ev.y, acc.y);
            acc.z = fmaf(a, ev.z, acc.z); acc.w = fmaf(a, ev.w, acc.w);
          }
          ((float4*)w)[y * 6 + zq] = acc;
        }
        for (int idx4 = tid; idx4 < 6 * S; idx4 += 256) {
          int s = idx4 / 6, q = idx4 - 6 * s;
          ((float4*)ebL)[idx4] = ((const float4*)(bbase + (size_t)tri(i, i + s) * 32))[q];
          ((float4*)ebR)[idx4] = ((const float4*)(bbase + (size_t)tri(i + s + 1, j) * 32))[q];
        }
        __syncthreads();
        if (tid < 8 * S) {
          int s = tid >> 3, q = tid & 7, y0 = q * 3;
          float pl = fmaxf(fmaxf(ebL[s * 24 + y0], ebL[s * 24 + y0 + 1]), ebL[s * 24 + y0 + 2]);
          float pr = fmaxf(fmaxf(ebR[s * 24 + y0], ebR[s * 24 + y0 + 1]), ebR[s * 24 + y0 + 2]);
          for (int off = 4; off; off >>= 1) {
            pl = fmaxf(pl, __shfl_xor(pl, off));
            pr = fmaxf(pr, __shfl_xor(pr, off));
          }
          if (q == 0) { mLs[s] = pl; mRs[s] = pr; }
        }
        __syncthreads();
        for (int idx = tid; idx < SN; idx += 256) {
          int s = idx / 24;
          ebL[idx] = __expf(ebL[idx] - mLs[s]);
          ebR[idx] = __expf(ebR[idx] - mRs[s]);
        }
        __syncthreads();
        for (int u = tid; u < 2 * SN; u += 256) {
          if (u < SN) {  // cL -> aL[tri(i,i+s)][y]; unique writer per level
            int s = u / 24, y = u - s * 24;
            const float4* w4 = (const float4*)(w + y * 24);
            const float4* r4 = (const float4*)(ebR + s * 24);
            float acc = 0;
#pragma unroll
            for (int q = 0; q < 6; q++) {
              float4 a = w4[q], c4 = r4[q];
              acc = fmaf(a.x, c4.x, fmaf(a.y, c4.y, fmaf(a.z, c4.z, fmaf(a.w, c4.w, acc))));
            }
            float val = __logf(fmaxf(acc, EPSV)) + ma + mRs[s];
            float* t = aLb + tri(i, i + s) * 24 + y;
            gstore(t, la2(gload(t), val));
          } else {       // cR -> aR[tri(i+s+1,j)][z]
            int u2 = u - SN;
            int s = u2 / 24, z = u2 - s * 24;
            float acc = 0;
            for (int y = 0; y < 24; y++) acc = fmaf(w[y * 24 + z], ebL[s * 24 + y], acc);
            float val = __logf(fmaxf(acc, EPSV)) + ma + mLs[s];
            float* t = aRb + tri(i + s + 1, j) * 24 + z;
            gstore(t, la2(gload(t), val));
          }
        }
      }
      // ---- arrive + poller ----
      __builtin_amdgcn_s_waitcnt(0);
      __syncthreads();
      if (tid == 0) storeu(slots + local, e);
      if (local == 0 && tid < 64) {
        for (;;) {
          unsigned v = e;
          if (tid < 32) v = loadu(slots + tid);
          if (__ballot(v >= e) == ~0ull) break;
          __builtin_amdgcn_s_sleep(1);
        }
        if (tid == 0) storeu(go, e);
      }
    }
  }
  if (tid == 0) { while (loadu(go) < 62u) __builtin_amdgcn_s_sleep(1); }
  __syncthreads();

  //================ mask logits + loss ================
  {
    float* p = wk;  // 768, layout [n*32 + t]
    float logZv = gload(bbase + 496 * 32);
    for (int c = tid; c < 768; c += 256) {
      int n = c >> 5, t = c & 31;
      int dA = tri(t, t) * 24 + n;
      float al = gload(aLb + dA), ar = gload(aRb + dA);
      p[c] = __expf(la2(al, ar) + bbase[(size_t)tri(t, t) * 32 + n] - logZv);
    }
    __syncthreads();
    int vbase = local * 1000;
    for (int pass = 0; pass < 2; pass++) {
      int o0 = tid + pass * 512, o1 = o0 + 256;
      bool v0ok = o0 < 1000, v1ok = o1 < 1000;
      int v0 = vbase + o0, v1 = vbase + o1;
      float vr0[24], vr1[24];
#pragma unroll
      for (int n = 0; n < 24; n++) {
        vr0[n] = v0ok ? vocab[n * 32000 + v0] : 0.f;
        vr1[n] = v1ok ? vocab[n * 32000 + v1] : 0.f;
      }
      float* ob0 = out + (size_t)b * 32 * 32000 + v0;
      float* ob1 = out + (size_t)b * 32 * 32000 + v1;
      for (int t4 = 0; t4 < 32; t4 += 4) {
        float a00 = 1e-6f, a01 = 1e-6f, a02 = 1e-6f, a03 = 1e-6f;
        float a10 = 1e-6f, a11 = 1e-6f, a12 = 1e-6f, a13 = 1e-6f;
#pragma unroll 6
        for (int n = 0; n < 24; n++) {
          float4 pv = *(const float4*)(p + n * 32 + t4);
          a00 = fmaf(pv.x, vr0[n], a00); a01 = fmaf(pv.y, vr0[n], a01);
          a02 = fmaf(pv.z, vr0[n], a02); a03 = fmaf(pv.w, vr0[n], a03);
          a10 = fmaf(pv.x, vr1[n], a10); a11 = fmaf(pv.y, vr1[n], a11);
          a12 = fmaf(pv.z, vr1[n], a12); a13 = fmaf(pv.w, vr1[n], a13);
        }
        if (v0ok) {
          ob0[(size_t)(t4 + 0) * 32000] = __logf(a00);
          ob0[(size_t)(t4 + 1) * 32000] = __logf(a01);
          ob0[(size_t)(t4 + 2) * 32000] = __logf(a02);
          ob0[(size_t)(t4 + 3) * 32000] = __logf(a03);
        }
        if (v1ok) {
          ob1[(size_t)(t4 + 0) * 32000] = __logf(a10);
          ob1[(size_t)(t4 + 1) * 32000] = __logf(a11);
          ob1[(size_t)(t4 + 2) * 32000] = __logf(a12);
          ob1[(size_t)(t4 + 3) * 32000] = __logf(a13);
        }
      }
    }
    if (blk == 0 && tid == 0) {
      while (loadu(done) < 16u) __builtin_amdgcn_s_sleep(2);
      float s = 0;
      for (int q = 0; q < 16; q++) s += gload(logZg + q);
      out[16384000] = -s / 16.0f;
    }
  }
}

// ---------------------------------------------------------------- launch
extern "C" void kernel_launch(void* const* d_in, const int* in_sizes, int n_in,
                              void* d_out, int out_size, void* d_ws, size_t ws_size,
                              hipStream_t stream) {
  (void)in_sizes; (void)n_in; (void)out_size; (void)ws_size;
  const float* g_seq = (const float*)d_in[0];
  const float* Theta = (const float*)d_in[1];
  const float* vocab = (const float*)d_in[2];
  const float* lng   = (const float*)d_in[3];
  const float* lnb   = (const float*)d_in[4];
  const float* W1    = (const float*)d_in[5];
  const float* bb1   = (const float*)d_in[6];
  const float* W2    = (const float*)d_in[7];
  const float* bb2   = (const float*)d_in[8];
  float* out = (float*)d_out;

  float* ws = (float*)d_ws;
  unsigned* cnt = (unsigned*)d_ws;            // ws[0..2048) counters (memset 0)
  float* logZg  = ws + 2048;                  // 16
  float* et_g   = ws + 4096;                  // 13824
  float* beta_g = ws + 18432;                 // 16 * 16896 = 270336
  float* aL_g   = beta_g + 16 * BSTRIDE;      // 202752
  float* aR_g   = aL_g + 16 * ASTRIDE;        // 202752

  hipMemsetAsync(d_ws, 0, 8192, stream);

  void* args[] = {(void*)&g_seq, (void*)&Theta, (void*)&vocab, (void*)&lng,
                  (void*)&lnb, (void*)&W1, (void*)&bb1, (void*)&W2, (void*)&bb2,
                  (void*)&out, (void*)&et_g, (void*)&beta_g, (void*)&aL_g,
                  (void*)&aR_g, (void*)&cnt, (void*)&logZg};
  hipLaunchCooperativeKernel((const void*)mega_kernel, dim3(512), dim3(256),
                             args, 0, stream);
}